// Round 17
// baseline (129.982 us; speedup 1.0000x reference)
//
#include <hip/hip_runtime.h>
#include <hip/hip_bf16.h>

// B=4, Y=64, X=64, C=256, H=8, F=32, 7x7 window (S=49). All I/O is FLOAT32.
// NOTE: measured dur_us includes ~55us of harness restore/re-poison
// (256MiB 0xAA fill at ~6TB/s) — kernel-side budget is dur_us - ~55.
static constexpr int NPOS = 4 * 64 * 64;   // 16384 rows
static constexpr int CD   = 256;
#define QSCALE (0.17677669529663687f * 1.4426950408889634f)  // 1/sqrt(32)*log2e

typedef __attribute__((ext_vector_type(8))) short bf16x8;   // MFMA A/B frag
typedef __attribute__((ext_vector_type(4))) float f32x4;    // MFMA C/D frag

__device__ __forceinline__ float bf2f(unsigned short u) {
    return __uint_as_float((unsigned int)u << 16);
}
__device__ __forceinline__ unsigned short bfbits(float f) {
    union { __hip_bfloat16 h; unsigned short u; } cv;
    cv.h = __float2bfloat16(f);
    return cv.u;
}
__device__ __forceinline__ unsigned int packbf2(float lo, float hi) {
    union { __hip_bfloat162 h; unsigned int u; } cv;
    cv.h.x = __float2bfloat16(lo);
    cv.h.y = __float2bfloat16(hi);
    return cv.u;
}
__device__ __forceinline__ uint4 pack8(float4 a, float4 b) {
    uint4 u;
    u.x = packbf2(a.x, a.y); u.y = packbf2(a.z, a.w);
    u.z = packbf2(b.x, b.y); u.w = packbf2(b.z, b.w);
    return u;
}
template<int CTRL>
__device__ __forceinline__ float dpp_mov(float v) {
    return __int_as_float(
        __builtin_amdgcn_update_dpp(0, __float_as_int(v), CTRL, 0xF, 0xF, true));
}
template<int IMM>
__device__ __forceinline__ float swz(float v) {
    return __int_as_float(__builtin_amdgcn_ds_swizzle(__float_as_int(v), IMM));
}

// ---------------------------------------------------------------------------
// convert: Wfrag (Wq|Wk|Wv b-frag bf16, 384KB) + pebf (pe^T b-frag,
// QSCALE-folded, 32KB) + Wofrag (128KB). 136 blocks x 256.
// ---------------------------------------------------------------------------
__global__ __launch_bounds__(256) void convert_kernel(
    const float* __restrict__ Wq, const float* __restrict__ Wk,
    const float* __restrict__ Wv, const float* __restrict__ Wo,
    const float* __restrict__ pe,
    __hip_bfloat16* __restrict__ Wfrag,
    __hip_bfloat16* __restrict__ pebf,
    __hip_bfloat16* __restrict__ Wofrag)
{
    int t = blockIdx.x * 256 + threadIdx.x;
    if (t < 24576) {
        int L = t & 63, ng = (t >> 6) & 7, s = (t >> 9) & 7, T = t >> 12;
        int mat = T >> 1;
        const float* src = (mat == 0) ? Wq : (mat == 1) ? Wk : Wv;
        int ncol  = (T & 1) * 128 + ng * 16 + (L & 15);
        int kbase = s * 32 + (L >> 4) * 8;
        __hip_bfloat16* dst = Wfrag + ((size_t)((T * 8 + s) * 8 + ng) * 64 + L) * 8;
#pragma unroll
        for (int j = 0; j < 8; ++j)
            dst[j] = __float2bfloat16(src[(kbase + j) * 256 + ncol]);
    } else if (t < 26624) {
        int u = t - 24576;
        int L = u & 63, Tn = (u >> 6) & 3, h = u >> 8;
        int s = Tn * 16 + (L & 15);
        int kbase = (L >> 4) * 8;
        __hip_bfloat16* dst = pebf + ((size_t)((h * 4 + Tn) * 64 + L)) * 8;
#pragma unroll
        for (int j = 0; j < 8; ++j) {
            float v = (s < 49) ? pe[s * 256 + h * 32 + kbase + j] * QSCALE : 0.f;
            dst[j] = __float2bfloat16(v);
        }
    } else if (t < 34816) {
        int u = t - 26624;
        int L = u & 63, ng = (u >> 6) & 7, s = (u >> 9) & 7, T = (u >> 12) & 1;
        int ncol  = T * 128 + ng * 16 + (L & 15);
        int kbase = s * 32 + (L >> 4) * 8;
        __hip_bfloat16* dst = Wofrag + ((size_t)((T * 8 + s) * 8 + ng) * 64 + L) * 8;
#pragma unroll
        for (int j = 0; j < 8; ++j)
            dst[j] = __float2bfloat16(Wo[(kbase + j) * 256 + ncol]);
    }
}

// ---------------------------------------------------------------------------
// Kernel 1: fused QKV GEMM reading x f32 directly (unchanged from r16).
// grid=(256,3): g=0->Q(+pe_q)->QA, 1->K*QSCALE->Kd, 2->V->Vt (LDS transpose,
// coalesced short4 stores). Wfrag b-frags + x both register-prefetched.
// ---------------------------------------------------------------------------
__global__ __launch_bounds__(256, 4) void qkv_mfma(
    const float* __restrict__ x,
    const __hip_bfloat16* __restrict__ Wfrag,
    const float* __restrict__ pe,
    unsigned short* __restrict__ QA,
    unsigned short* __restrict__ Kd,
    unsigned short* __restrict__ Vt)
{
    __shared__ __align__(16) unsigned short smem[256 * 68];
    short* As0 = (short*)smem;
    short* As1 = As0 + 2048;
    const int t = threadIdx.x;
    const int rowbase = blockIdx.x * 64;
    const int g = blockIdx.y;
    const int L = t & 63;
    const int wave = t >> 6;
    const int quad = L >> 4, lrow = L & 15;
    const int T = g * 2 + (wave >> 1);
    const int ngb = (wave & 1) * 4;

    f32x4 acc[4][4];
#pragma unroll
    for (int i = 0; i < 4; ++i)
#pragma unroll
        for (int j = 0; j < 4; ++j) acc[i][j] = (f32x4){0.f, 0.f, 0.f, 0.f};

    const float* xsrc = x + (size_t)(rowbase + (t >> 2)) * CD + (t & 3) * 8;
    const __hip_bfloat16* wbase = Wfrag + ((size_t)(T * 8 * 8 + ngb) * 64 + L) * 8;

    float4 f0 = ((const float4*)xsrc)[0];
    float4 f1 = ((const float4*)xsrc)[1];
    ((uint4*)As0)[t] = pack8(f0, f1);
    f0 = ((const float4*)(xsrc + 32))[0];
    f1 = ((const float4*)(xsrc + 32))[1];

    bf16x8 bfr[4];
#pragma unroll
    for (int j = 0; j < 4; ++j)
        bfr[j] = *(const bf16x8*)(wbase + (size_t)j * 64 * 8);
    __syncthreads();

#pragma unroll
    for (int s = 0; s < 8; ++s) {
        bf16x8 nbfr[4];
        if (s < 7) {
#pragma unroll
            for (int j = 0; j < 4; ++j)
                nbfr[j] = *(const bf16x8*)(wbase + (size_t)((s + 1) * 8 + j) * 64 * 8);
        }
        if (s < 7) {
            ((uint4*)((s & 1) ? As0 : As1))[t] = pack8(f0, f1);
            if (s < 6) {
                f0 = ((const float4*)(xsrc + (s + 2) * 32))[0];
                f1 = ((const float4*)(xsrc + (s + 2) * 32))[1];
            }
        }
        const short* Ab = (s & 1) ? As1 : As0;
#pragma unroll
        for (int i = 0; i < 4; ++i) {
            bf16x8 af = *(const bf16x8*)(Ab + (i * 16 + lrow) * 32 + quad * 8);
#pragma unroll
            for (int j = 0; j < 4; ++j)
                acc[i][j] = __builtin_amdgcn_mfma_f32_16x16x32_bf16(af, bfr[j], acc[i][j], 0, 0, 0);
        }
        __syncthreads();
#pragma unroll
        for (int j = 0; j < 4; ++j) bfr[j] = nbfr[j];
    }

    if (g == 0) {
#pragma unroll
        for (int i = 0; i < 4; ++i)
#pragma unroll
            for (int r = 0; r < 4; ++r) {
                int row = rowbase + i * 16 + quad * 4 + r;
                int yy = (row >> 6) & 63, xx = row & 63;
                int cy = min(max(yy, 3), 60), cx = min(max(xx, 3), 60);
                int qidx = (yy - cy + 3) * 7 + (xx - cx + 3);
#pragma unroll
                for (int j = 0; j < 4; ++j) {
                    int c = wave * 64 + j * 16 + lrow;
                    QA[(size_t)row * CD + c] = bfbits(acc[i][j][r] + pe[qidx * 256 + c]);
                }
            }
    } else if (g == 1) {
#pragma unroll
        for (int i = 0; i < 4; ++i)
#pragma unroll
            for (int r = 0; r < 4; ++r) {
                int row = rowbase + i * 16 + quad * 4 + r;
#pragma unroll
                for (int j = 0; j < 4; ++j) {
                    int c = wave * 64 + j * 16 + lrow;
                    Kd[(size_t)row * CD + c] = bfbits(acc[i][j][r] * QSCALE);
                }
            }
    } else {
        unsigned short* vt = smem;
#pragma unroll
        for (int i = 0; i < 4; ++i)
#pragma unroll
            for (int j = 0; j < 4; ++j) {
                int c = wave * 64 + j * 16 + lrow;
                int row0 = i * 16 + quad * 4;
                *(unsigned int*)&vt[c * 68 + row0] =
                    (unsigned int)bfbits(acc[i][j][0]) | ((unsigned int)bfbits(acc[i][j][1]) << 16);
                *(unsigned int*)&vt[c * 68 + row0 + 2] =
                    (unsigned int)bfbits(acc[i][j][2]) | ((unsigned int)bfbits(acc[i][j][3]) << 16);
            }
        __syncthreads();
        const int grp = t >> 4, lig = t & 15;
        const int row_off = lig * 4;
#pragma unroll
        for (int pass = 0; pass < 16; ++pass) {
            int c = pass * 16 + grp;
            *(ushort4*)(Vt + (size_t)c * 16384 + rowbase + row_off) =
                *(const ushort4*)&vt[c * 68 + row_off];
        }
    }
}

// ---------------------------------------------------------------------------
// Kernel 2: FUSED attention + output projection, 512 thr / 8 waves = one
// 16-position x-run; wave w = head w.
// NEW (r17): (a) P LDS round-trip pipelined ACROSS dy iterations via
// double-buffered ps — at iter dy we read P(dy-1)'s A-frag (from the buffer
// written LAST iteration, long drained) and run PV(dy-1) BEFORE writing
// P(dy); the write->waitcnt->read->MFMA chain leaves the critical path.
// (b) loop-invariant hoisting: band index/mask & qp offsets are dy-invariant.
// ---------------------------------------------------------------------------
__global__ __launch_bounds__(512) void attn_oproj(
    const unsigned short* __restrict__ QA,   // bf16 [pos][256] (Q)
    const unsigned short* __restrict__ Kd,
    const unsigned short* __restrict__ Vt,
    const __hip_bfloat16* __restrict__ pebf,
    const __hip_bfloat16* __restrict__ Wofrag,
    float* __restrict__ out)
{
    __shared__ unsigned short qpes[8][16 * 64];              // 16 KB (bf16)
    __shared__ __align__(16) unsigned short ps[8][2][640];   // 20 KB (dbuf P)
    __shared__ __align__(16) unsigned short At[16 * 264];    // 8.25 KB
    const int t = threadIdx.x, w = t >> 6, L = t & 63;
    const int lrow = L & 15, quad = L >> 4;
    const int pos0 = blockIdx.x * 16;
    const int x0 = pos0 & 63;
    const int yy = (pos0 >> 6) & 63, bb = pos0 >> 12;
    const int cy = min(max(yy, 3), 60);
    const int h = w;

    const int kc0 = min(max(x0 - 8 + lrow, 0), 63);
    const int kc1 = min(max(x0 + 8 + lrow, 0), 63);
    const f32x4 zero = {0.f, 0.f, 0.f, 0.f};
    unsigned short* qp = qpes[w];

    // dy-invariant band indices and masks (hoisted out of the main loop)
    int qi0[4], qi1[4];
    float mk0[4], mk1[4];
#pragma unroll
    for (int r = 0; r < 4; ++r) {
        const int i = quad * 4 + r;
        const int cxr = min(max(x0 + i, 3), 60) - x0 + 5;
        int dx3a = lrow - cxr;
        qi0[r] = i * 64 + min(max(dx3a, 0), 6);
        mk0[r] = ((unsigned)dx3a <= 6u) ? 1.f : 0.f;
        int dx3b = 16 + lrow - cxr;
        qi1[r] = i * 64 + min(max(dx3b, 0), 6);
        mk1[r] = ((unsigned)dx3b <= 6u) ? 1.f : 0.f;
    }

    const bf16x8 qa = *(const bf16x8*)(QA + (size_t)(pos0 + lrow) * 256 + h * 32 + quad * 8);

    // Qpe[i][s] via 4 MFMAs -> LDS (bf16)
#pragma unroll
    for (int Tn = 0; Tn < 4; ++Tn) {
        bf16x8 bp = *(const bf16x8*)(pebf + ((size_t)((h * 4 + Tn) * 64 + L)) * 8);
        f32x4 c = __builtin_amdgcn_mfma_f32_16x16x32_bf16(qa, bp, zero, 0, 0, 0);
#pragma unroll
        for (int r = 0; r < 4; ++r)
            qp[(quad * 4 + r) * 64 + Tn * 16 + lrow] = bfbits(c[r]);
    }
    __builtin_amdgcn_s_waitcnt(0xc07f);

    float lacc[4] = {0.f, 0.f, 0.f, 0.f};
    f32x4 o0 = zero, o1 = zero;
    const int rowbase0 = bb * 4096 + (cy - 3) * 64;

    const size_t koff = h * 32 + quad * 8;
    const unsigned short* Vb0 = Vt + (size_t)(h * 32 + lrow) * 16384 + x0 - 8 + quad * 8;
    const unsigned short* Vb1 = Vt + (size_t)(h * 32 + 16 + lrow) * 16384 + x0 - 8 + quad * 8;
    const int pwofs = (quad * 4) * 40 + lrow;    // + r*40 (+16 tile1) at write

    // ---- dy = 0 prologue ----
    bf16x8 bk0 = *(const bf16x8*)(Kd + (size_t)(rowbase0 + kc0) * 256 + koff);
    bf16x8 bk1 = *(const bf16x8*)(Kd + (size_t)(rowbase0 + kc1) * 256 + koff);
    bf16x8 bv0p = *(const bf16x8*)(Vb0 + rowbase0);   // V(0), consumed iter 1
    bf16x8 bv1p = *(const bf16x8*)(Vb1 + rowbase0);
    {
        f32x4 s0 = __builtin_amdgcn_mfma_f32_16x16x32_bf16(qa, bk0, zero, 0, 0, 0);
        f32x4 s1 = __builtin_amdgcn_mfma_f32_16x16x32_bf16(qa, bk1, zero, 0, 0, 0);
        bk0 = *(const bf16x8*)(Kd + (size_t)(rowbase0 + 64 + kc0) * 256 + koff); // K(1)
        bk1 = *(const bf16x8*)(Kd + (size_t)(rowbase0 + 64 + kc1) * 256 + koff);
        unsigned short* pwr = &ps[w][0][0];
#pragma unroll
        for (int r = 0; r < 4; ++r) {
            float e0 = exp2f(s0[r] + bf2f(qp[qi0[r]])) * mk0[r];
            lacc[r] += e0;
            pwr[pwofs + r * 40] = bfbits(e0);
            float e1 = exp2f(s1[r] + bf2f(qp[qi1[r]])) * mk1[r];
            lacc[r] += e1;
            pwr[pwofs + r * 40 + 16] = bfbits(e1);
        }
    }

    int qpofs = 7;
    for (int dy = 1; dy < 7; ++dy) {
        const int rp = rowbase0 + dy * 64;
        bf16x8 bv0n = *(const bf16x8*)(Vb0 + rp);     // V(dy), consumed next iter
        bf16x8 bv1n = *(const bf16x8*)(Vb1 + rp);
        f32x4 s0 = __builtin_amdgcn_mfma_f32_16x16x32_bf16(qa, bk0, zero, 0, 0, 0);
        f32x4 s1 = __builtin_amdgcn_mfma_f32_16x16x32_bf16(qa, bk1, zero, 0, 0, 0);
        if (dy < 6) {                                 // prefetch K(dy+1)
            bk0 = *(const bf16x8*)(Kd + (size_t)(rp + 64 + kc0) * 256 + koff);
            bk1 = *(const bf16x8*)(Kd + (size_t)(rp + 64 + kc1) * 256 + koff);
        }
        // read P(dy-1) A-frag from the OTHER buffer (written last iter,
        // drained) and run PV(dy-1) before writing P(dy):
        const bf16x8 pa = *(const bf16x8*)(&ps[w][(dy - 1) & 1][0] + lrow * 40 + quad * 8);
        o0 = __builtin_amdgcn_mfma_f32_16x16x32_bf16(pa, bv0p, o0, 0, 0, 0);
        o1 = __builtin_amdgcn_mfma_f32_16x16x32_bf16(pa, bv1p, o1, 0, 0, 0);
        unsigned short* pwr = &ps[w][dy & 1][0];
#pragma unroll
        for (int r = 0; r < 4; ++r) {
            float e0 = exp2f(s0[r] + bf2f(qp[qi0[r] + qpofs])) * mk0[r];
            lacc[r] += e0;
            pwr[pwofs + r * 40] = bfbits(e0);
            float e1 = exp2f(s1[r] + bf2f(qp[qi1[r] + qpofs])) * mk1[r];
            lacc[r] += e1;
            pwr[pwofs + r * 40 + 16] = bfbits(e1);
        }
        qpofs += 7;
        bv0p = bv0n; bv1p = bv1n;
    }
    {   // epilogue: PV(6) — P(6) is in buffer 0 (6&1)
        const bf16x8 pa = *(const bf16x8*)(&ps[w][0][0] + lrow * 40 + quad * 8);
        o0 = __builtin_amdgcn_mfma_f32_16x16x32_bf16(pa, bv0p, o0, 0, 0, 0);
        o1 = __builtin_amdgcn_mfma_f32_16x16x32_bf16(pa, bv1p, o1, 0, 0, 0);
    }

    // l reduce + store A fragment into LDS At (16 rows x 264 stride)
#pragma unroll
    for (int r = 0; r < 4; ++r) {
        float v = lacc[r];
        v += dpp_mov<0xB1>(v);
        v += dpp_mov<0x4E>(v);
        v += swz<0x101F>(v);
        v += swz<0x201F>(v);
        const float inv = 1.f / (v + 1e-8f);
        const int arow = quad * 4 + r;
        At[arow * 264 + h * 32 + lrow]      = bfbits(o0[r] * inv);
        At[arow * 264 + h * 32 + 16 + lrow] = bfbits(o1[r] * inv);
    }
    __syncthreads();

    // ---- oproj phase: out[pos0..+16][w*32..+32] = At @ Wo ------------------
    const int T = w >> 2;
    const int ngb = (w & 3) * 2;
    f32x4 acc[2];
    acc[0] = zero; acc[1] = zero;

#pragma unroll
    for (int s = 0; s < 8; ++s) {
        bf16x8 bfr[2];
#pragma unroll
        for (int j = 0; j < 2; ++j)
            bfr[j] = *(const bf16x8*)(Wofrag +
                      ((size_t)((T * 8 + s) * 8 + ngb + j) * 64 + L) * 8);
        bf16x8 af = *(const bf16x8*)(At + lrow * 264 + s * 32 + quad * 8);
#pragma unroll
        for (int j = 0; j < 2; ++j)
            acc[j] = __builtin_amdgcn_mfma_f32_16x16x32_bf16(af, bfr[j], acc[j], 0, 0, 0);
    }

#pragma unroll
    for (int r = 0; r < 4; ++r) {
        int row = pos0 + quad * 4 + r;
#pragma unroll
        for (int j = 0; j < 2; ++j) {
            int c = w * 32 + j * 16 + lrow;
            out[(size_t)row * CD + c] = acc[j][r];
        }
    }
}

// ---------------------------------------------------------------------------
// Memory plan (ws ~256 MiB; we use ~25 MB):
//   ws[ 0,  8MB): QA bf16 (Q + pe_q)
//   ws[ 8, 16MB): Kd bf16 (QSCALE-folded; tail absorbs Vt underflow reads)
//   ws[16, 24MB): Vt bf16 transposed [ch][16384]; 4KB pad after
//   ws[24MB+4KB, +544KB): Wfrag 384KB | pebf 32KB | Wofrag 128KB
// ---------------------------------------------------------------------------
extern "C" void kernel_launch(void* const* d_in, const int* in_sizes, int n_in,
                              void* d_out, int out_size, void* d_ws, size_t ws_size,
                              hipStream_t stream)
{
    const float* x  = (const float*)d_in[0];
    const float* Wq = (const float*)d_in[1];
    const float* Wk = (const float*)d_in[2];
    const float* Wv = (const float*)d_in[3];
    const float* Wo = (const float*)d_in[4];
    const float* pe = (const float*)d_in[5];
    float* out = (float*)d_out;

    char* ws = (char*)d_ws;
    unsigned short* QA = (unsigned short*)ws;
    unsigned short* Kd = (unsigned short*)(ws + (8u << 20));
    unsigned short* Vt = (unsigned short*)(ws + (16u << 20));
    char* fr = ws + (24u << 20) + 4096;
    __hip_bfloat16* Wfrag  = (__hip_bfloat16*)fr;
    __hip_bfloat16* pebf   = (__hip_bfloat16*)(fr + (384u << 10));
    __hip_bfloat16* Wofrag = (__hip_bfloat16*)(fr + (416u << 10));

    convert_kernel<<<136, 256, 0, stream>>>(Wq, Wk, Wv, Wo, pe, Wfrag, pebf, Wofrag);
    qkv_mfma<<<dim3(256, 3), 256, 0, stream>>>(x, Wfrag, pe, QA, Kd, Vt);
    attn_oproj<<<1024, 512, 0, stream>>>(QA, Kd, Vt, pebf, Wofrag, out);
}

// Round 18
// 122.814 us; speedup vs baseline: 1.0584x; 1.0584x over previous
//
#include <hip/hip_runtime.h>
#include <hip/hip_bf16.h>

// B=4, Y=64, X=64, C=256, H=8, F=32, 7x7 window (S=49). All I/O is FLOAT32.
// NOTE: measured dur_us includes ~55us of harness restore/re-poison
// (256MiB 0xAA fill at ~6TB/s) — kernel-side budget is dur_us - ~55.
static constexpr int NPOS = 4 * 64 * 64;   // 16384 rows
static constexpr int CD   = 256;
#define QSCALE (0.17677669529663687f * 1.4426950408889634f)  // 1/sqrt(32)*log2e

typedef __attribute__((ext_vector_type(8))) short bf16x8;   // MFMA A/B frag
typedef __attribute__((ext_vector_type(4))) float f32x4;    // MFMA C/D frag

__device__ __forceinline__ float bf2f(unsigned short u) {
    return __uint_as_float((unsigned int)u << 16);
}
__device__ __forceinline__ unsigned short bfbits(float f) {
    union { __hip_bfloat16 h; unsigned short u; } cv;
    cv.h = __float2bfloat16(f);
    return cv.u;
}
__device__ __forceinline__ unsigned int packbf2(float lo, float hi) {
    union { __hip_bfloat162 h; unsigned int u; } cv;
    cv.h.x = __float2bfloat16(lo);
    cv.h.y = __float2bfloat16(hi);
    return cv.u;
}
__device__ __forceinline__ uint4 pack8(float4 a, float4 b) {
    uint4 u;
    u.x = packbf2(a.x, a.y); u.y = packbf2(a.z, a.w);
    u.z = packbf2(b.x, b.y); u.w = packbf2(b.z, b.w);
    return u;
}
template<int CTRL>
__device__ __forceinline__ float dpp_mov(float v) {
    return __int_as_float(
        __builtin_amdgcn_update_dpp(0, __float_as_int(v), CTRL, 0xF, 0xF, true));
}
template<int IMM>
__device__ __forceinline__ float swz(float v) {
    return __int_as_float(__builtin_amdgcn_ds_swizzle(__float_as_int(v), IMM));
}

// ---------------------------------------------------------------------------
// convert: Wfrag (Wq|Wk|Wv b-frag bf16, 384KB) + pebf (pe^T b-frag,
// QSCALE-folded, 32KB) + Wofrag (128KB). 136 blocks x 256.
// ---------------------------------------------------------------------------
__global__ __launch_bounds__(256) void convert_kernel(
    const float* __restrict__ Wq, const float* __restrict__ Wk,
    const float* __restrict__ Wv, const float* __restrict__ Wo,
    const float* __restrict__ pe,
    __hip_bfloat16* __restrict__ Wfrag,
    __hip_bfloat16* __restrict__ pebf,
    __hip_bfloat16* __restrict__ Wofrag)
{
    int t = blockIdx.x * 256 + threadIdx.x;
    if (t < 24576) {
        int L = t & 63, ng = (t >> 6) & 7, s = (t >> 9) & 7, T = t >> 12;
        int mat = T >> 1;
        const float* src = (mat == 0) ? Wq : (mat == 1) ? Wk : Wv;
        int ncol  = (T & 1) * 128 + ng * 16 + (L & 15);
        int kbase = s * 32 + (L >> 4) * 8;
        __hip_bfloat16* dst = Wfrag + ((size_t)((T * 8 + s) * 8 + ng) * 64 + L) * 8;
#pragma unroll
        for (int j = 0; j < 8; ++j)
            dst[j] = __float2bfloat16(src[(kbase + j) * 256 + ncol]);
    } else if (t < 26624) {
        int u = t - 24576;
        int L = u & 63, Tn = (u >> 6) & 3, h = u >> 8;
        int s = Tn * 16 + (L & 15);
        int kbase = (L >> 4) * 8;
        __hip_bfloat16* dst = pebf + ((size_t)((h * 4 + Tn) * 64 + L)) * 8;
#pragma unroll
        for (int j = 0; j < 8; ++j) {
            float v = (s < 49) ? pe[s * 256 + h * 32 + kbase + j] * QSCALE : 0.f;
            dst[j] = __float2bfloat16(v);
        }
    } else if (t < 34816) {
        int u = t - 26624;
        int L = u & 63, ng = (u >> 6) & 7, s = (u >> 9) & 7, T = (u >> 12) & 1;
        int ncol  = T * 128 + ng * 16 + (L & 15);
        int kbase = s * 32 + (L >> 4) * 8;
        __hip_bfloat16* dst = Wofrag + ((size_t)((T * 8 + s) * 8 + ng) * 64 + L) * 8;
#pragma unroll
        for (int j = 0; j < 8; ++j)
            dst[j] = __float2bfloat16(Wo[(kbase + j) * 256 + ncol]);
    }
}

// ---------------------------------------------------------------------------
// Kernel 1: fused QKV GEMM reading x f32 directly (unchanged from r16).
// grid=(256,3): g=0->Q(+pe_q)->QA, 1->K*QSCALE->Kd, 2->V->Vt (LDS transpose,
// coalesced short4 stores). Wfrag b-frags + x both register-prefetched.
// ---------------------------------------------------------------------------
__global__ __launch_bounds__(256, 4) void qkv_mfma(
    const float* __restrict__ x,
    const __hip_bfloat16* __restrict__ Wfrag,
    const float* __restrict__ pe,
    unsigned short* __restrict__ QA,
    unsigned short* __restrict__ Kd,
    unsigned short* __restrict__ Vt)
{
    __shared__ __align__(16) unsigned short smem[256 * 68];
    short* As0 = (short*)smem;
    short* As1 = As0 + 2048;
    const int t = threadIdx.x;
    const int rowbase = blockIdx.x * 64;
    const int g = blockIdx.y;
    const int L = t & 63;
    const int wave = t >> 6;
    const int quad = L >> 4, lrow = L & 15;
    const int T = g * 2 + (wave >> 1);
    const int ngb = (wave & 1) * 4;

    f32x4 acc[4][4];
#pragma unroll
    for (int i = 0; i < 4; ++i)
#pragma unroll
        for (int j = 0; j < 4; ++j) acc[i][j] = (f32x4){0.f, 0.f, 0.f, 0.f};

    const float* xsrc = x + (size_t)(rowbase + (t >> 2)) * CD + (t & 3) * 8;
    const __hip_bfloat16* wbase = Wfrag + ((size_t)(T * 8 * 8 + ngb) * 64 + L) * 8;

    float4 f0 = ((const float4*)xsrc)[0];
    float4 f1 = ((const float4*)xsrc)[1];
    ((uint4*)As0)[t] = pack8(f0, f1);
    f0 = ((const float4*)(xsrc + 32))[0];
    f1 = ((const float4*)(xsrc + 32))[1];

    bf16x8 bfr[4];
#pragma unroll
    for (int j = 0; j < 4; ++j)
        bfr[j] = *(const bf16x8*)(wbase + (size_t)j * 64 * 8);
    __syncthreads();

#pragma unroll
    for (int s = 0; s < 8; ++s) {
        bf16x8 nbfr[4];
        if (s < 7) {
#pragma unroll
            for (int j = 0; j < 4; ++j)
                nbfr[j] = *(const bf16x8*)(wbase + (size_t)((s + 1) * 8 + j) * 64 * 8);
        }
        if (s < 7) {
            ((uint4*)((s & 1) ? As0 : As1))[t] = pack8(f0, f1);
            if (s < 6) {
                f0 = ((const float4*)(xsrc + (s + 2) * 32))[0];
                f1 = ((const float4*)(xsrc + (s + 2) * 32))[1];
            }
        }
        const short* Ab = (s & 1) ? As1 : As0;
#pragma unroll
        for (int i = 0; i < 4; ++i) {
            bf16x8 af = *(const bf16x8*)(Ab + (i * 16 + lrow) * 32 + quad * 8);
#pragma unroll
            for (int j = 0; j < 4; ++j)
                acc[i][j] = __builtin_amdgcn_mfma_f32_16x16x32_bf16(af, bfr[j], acc[i][j], 0, 0, 0);
        }
        __syncthreads();
#pragma unroll
        for (int j = 0; j < 4; ++j) bfr[j] = nbfr[j];
    }

    if (g == 0) {
#pragma unroll
        for (int i = 0; i < 4; ++i)
#pragma unroll
            for (int r = 0; r < 4; ++r) {
                int row = rowbase + i * 16 + quad * 4 + r;
                int yy = (row >> 6) & 63, xx = row & 63;
                int cy = min(max(yy, 3), 60), cx = min(max(xx, 3), 60);
                int qidx = (yy - cy + 3) * 7 + (xx - cx + 3);
#pragma unroll
                for (int j = 0; j < 4; ++j) {
                    int c = wave * 64 + j * 16 + lrow;
                    QA[(size_t)row * CD + c] = bfbits(acc[i][j][r] + pe[qidx * 256 + c]);
                }
            }
    } else if (g == 1) {
#pragma unroll
        for (int i = 0; i < 4; ++i)
#pragma unroll
            for (int r = 0; r < 4; ++r) {
                int row = rowbase + i * 16 + quad * 4 + r;
#pragma unroll
                for (int j = 0; j < 4; ++j) {
                    int c = wave * 64 + j * 16 + lrow;
                    Kd[(size_t)row * CD + c] = bfbits(acc[i][j][r] * QSCALE);
                }
            }
    } else {
        unsigned short* vt = smem;
#pragma unroll
        for (int i = 0; i < 4; ++i)
#pragma unroll
            for (int j = 0; j < 4; ++j) {
                int c = wave * 64 + j * 16 + lrow;
                int row0 = i * 16 + quad * 4;
                *(unsigned int*)&vt[c * 68 + row0] =
                    (unsigned int)bfbits(acc[i][j][0]) | ((unsigned int)bfbits(acc[i][j][1]) << 16);
                *(unsigned int*)&vt[c * 68 + row0 + 2] =
                    (unsigned int)bfbits(acc[i][j][2]) | ((unsigned int)bfbits(acc[i][j][3]) << 16);
            }
        __syncthreads();
        const int grp = t >> 4, lig = t & 15;
        const int row_off = lig * 4;
#pragma unroll
        for (int pass = 0; pass < 16; ++pass) {
            int c = pass * 16 + grp;
            *(ushort4*)(Vt + (size_t)c * 16384 + rowbase + row_off) =
                *(const ushort4*)&vt[c * 68 + row_off];
        }
    }
}

// ---------------------------------------------------------------------------
// Kernel 2: FUSED attention + output projection, 512 thr / 8 waves = one
// 16-position x-run; wave w = head w. r16 P round-trip restored (r17's
// double-buffered P regressed: +1.67M LDS conflicts, +5us).
// NEW (r18): XCD-AWARE BLOCK SWIZZLE — tile = ((bid&7)<<7)|(bid>>3), so
// XCD r (= bid&7 under round-robin dispatch) owns a CONTIGUOUS spatial
// region (half-batch y-band, K+V working set ~2.4MB, fits its 4MB L2).
// r17 counters showed 108MB HBM FETCH (vs ~26MB ideal) because spatially
// adjacent tiles were scattered across non-coherent per-XCD L2s.
// ---------------------------------------------------------------------------
__global__ __launch_bounds__(512) void attn_oproj(
    const unsigned short* __restrict__ QA,   // bf16 [pos][256] (Q)
    const unsigned short* __restrict__ Kd,
    const unsigned short* __restrict__ Vt,
    const __hip_bfloat16* __restrict__ pebf,
    const __hip_bfloat16* __restrict__ Wofrag,
    float* __restrict__ out)
{
    __shared__ unsigned short qpes[8][16 * 64];              // 16 KB (bf16)
    __shared__ __align__(16) unsigned short ps[8][16 * 40];  // 10 KB
    __shared__ __align__(16) unsigned short At[16 * 264];    // 8.25 KB
    const int t = threadIdx.x, w = t >> 6, L = t & 63;
    const int lrow = L & 15, quad = L >> 4;
    const int bid = blockIdx.x;
    const int tile = ((bid & 7) << 7) | (bid >> 3);   // XCD-local spatial region
    const int pos0 = tile * 16;
    const int x0 = pos0 & 63;
    const int yy = (pos0 >> 6) & 63, bb = pos0 >> 12;
    const int cy = min(max(yy, 3), 60);
    const int h = w;

    const int kc0 = min(max(x0 - 8 + lrow, 0), 63);
    const int kc1 = min(max(x0 + 8 + lrow, 0), 63);
    const f32x4 zero = {0.f, 0.f, 0.f, 0.f};
    unsigned short* qp = qpes[w];
    unsigned short* pw = ps[w];

    // dy-invariant band indices and masks
    int qi0[4], qi1[4];
    float mk0[4], mk1[4];
#pragma unroll
    for (int r = 0; r < 4; ++r) {
        const int i = quad * 4 + r;
        const int cxr = min(max(x0 + i, 3), 60) - x0 + 5;
        int dx3a = lrow - cxr;
        qi0[r] = i * 64 + min(max(dx3a, 0), 6);
        mk0[r] = ((unsigned)dx3a <= 6u) ? 1.f : 0.f;
        int dx3b = 16 + lrow - cxr;
        qi1[r] = i * 64 + min(max(dx3b, 0), 6);
        mk1[r] = ((unsigned)dx3b <= 6u) ? 1.f : 0.f;
    }

    const bf16x8 qa = *(const bf16x8*)(QA + (size_t)(pos0 + lrow) * 256 + h * 32 + quad * 8);

    // Qpe[i][s] via 4 MFMAs -> LDS (bf16)
#pragma unroll
    for (int Tn = 0; Tn < 4; ++Tn) {
        bf16x8 bp = *(const bf16x8*)(pebf + ((size_t)((h * 4 + Tn) * 64 + L)) * 8);
        f32x4 c = __builtin_amdgcn_mfma_f32_16x16x32_bf16(qa, bp, zero, 0, 0, 0);
#pragma unroll
        for (int r = 0; r < 4; ++r)
            qp[(quad * 4 + r) * 64 + Tn * 16 + lrow] = bfbits(c[r]);
    }
    __builtin_amdgcn_s_waitcnt(0xc07f);

    float lacc[4] = {0.f, 0.f, 0.f, 0.f};
    f32x4 o0 = zero, o1 = zero;
    int rowpos = bb * 4096 + (cy - 3) * 64;

    const size_t koff = h * 32 + quad * 8;
    const size_t voff0 = (size_t)(h * 32 + lrow) * 16384 + x0 - 8 + quad * 8;
    const size_t voff1 = (size_t)(h * 32 + 16 + lrow) * 16384 + x0 - 8 + quad * 8;
    bf16x8 bk0 = *(const bf16x8*)(Kd + (size_t)(rowpos + kc0) * 256 + koff);
    bf16x8 bk1 = *(const bf16x8*)(Kd + (size_t)(rowpos + kc1) * 256 + koff);
    bf16x8 bv0 = *(const bf16x8*)(Vt + voff0 + rowpos);
    bf16x8 bv1 = *(const bf16x8*)(Vt + voff1 + rowpos);

    int qpofs = 0;
    for (int dy = 0; dy < 7; ++dy) {
        const int rnext = rowpos + 64;
        bf16x8 nk0, nk1, nv0, nv1;
        if (dy < 6) {                      // dy+1 loads in flight across phase
            nk0 = *(const bf16x8*)(Kd + (size_t)(rnext + kc0) * 256 + koff);
            nk1 = *(const bf16x8*)(Kd + (size_t)(rnext + kc1) * 256 + koff);
            nv0 = *(const bf16x8*)(Vt + voff0 + rnext);
            nv1 = *(const bf16x8*)(Vt + voff1 + rnext);
        }
        f32x4 sc0 = __builtin_amdgcn_mfma_f32_16x16x32_bf16(qa, bk0, zero, 0, 0, 0);
        f32x4 sc1 = __builtin_amdgcn_mfma_f32_16x16x32_bf16(qa, bk1, zero, 0, 0, 0);
#pragma unroll
        for (int r = 0; r < 4; ++r) {
            float e0 = exp2f(sc0[r] + bf2f(qp[qi0[r] + qpofs])) * mk0[r];
            lacc[r] += e0;
            pw[(quad * 4 + r) * 40 + lrow] = bfbits(e0);
            float e1 = exp2f(sc1[r] + bf2f(qp[qi1[r] + qpofs])) * mk1[r];
            lacc[r] += e1;
            pw[(quad * 4 + r) * 40 + 16 + lrow] = bfbits(e1);
        }
        __builtin_amdgcn_s_waitcnt(0xc07f);
        const bf16x8 pa = *(const bf16x8*)(pw + lrow * 40 + quad * 8);
        o0 = __builtin_amdgcn_mfma_f32_16x16x32_bf16(pa, bv0, o0, 0, 0, 0);
        o1 = __builtin_amdgcn_mfma_f32_16x16x32_bf16(pa, bv1, o1, 0, 0, 0);
        bk0 = nk0; bk1 = nk1; bv0 = nv0; bv1 = nv1;
        rowpos = rnext;
        qpofs += 7;
    }

    // l reduce + store A fragment into LDS At (16 rows x 264 stride)
#pragma unroll
    for (int r = 0; r < 4; ++r) {
        float v = lacc[r];
        v += dpp_mov<0xB1>(v);
        v += dpp_mov<0x4E>(v);
        v += swz<0x101F>(v);
        v += swz<0x201F>(v);
        const float inv = 1.f / (v + 1e-8f);
        const int arow = quad * 4 + r;
        At[arow * 264 + h * 32 + lrow]      = bfbits(o0[r] * inv);
        At[arow * 264 + h * 32 + 16 + lrow] = bfbits(o1[r] * inv);
    }
    __syncthreads();

    // ---- oproj phase: out[pos0..+16][w*32..+32] = At @ Wo ------------------
    const int T = w >> 2;
    const int ngb = (w & 3) * 2;
    f32x4 acc[2];
    acc[0] = zero; acc[1] = zero;

#pragma unroll
    for (int s = 0; s < 8; ++s) {
        bf16x8 bfr[2];
#pragma unroll
        for (int j = 0; j < 2; ++j)
            bfr[j] = *(const bf16x8*)(Wofrag +
                      ((size_t)((T * 8 + s) * 8 + ngb + j) * 64 + L) * 8);
        bf16x8 af = *(const bf16x8*)(At + lrow * 264 + s * 32 + quad * 8);
#pragma unroll
        for (int j = 0; j < 2; ++j)
            acc[j] = __builtin_amdgcn_mfma_f32_16x16x32_bf16(af, bfr[j], acc[j], 0, 0, 0);
    }

#pragma unroll
    for (int r = 0; r < 4; ++r) {
        int row = pos0 + quad * 4 + r;
#pragma unroll
        for (int j = 0; j < 2; ++j) {
            int c = w * 32 + j * 16 + lrow;
            out[(size_t)row * CD + c] = acc[j][r];
        }
    }
}

// ---------------------------------------------------------------------------
// Memory plan (ws ~256 MiB; we use ~25 MB):
//   ws[ 0,  8MB): QA bf16 (Q + pe_q)
//   ws[ 8, 16MB): Kd bf16 (QSCALE-folded; tail absorbs Vt underflow reads)
//   ws[16, 24MB): Vt bf16 transposed [ch][16384]; 4KB pad after
//   ws[24MB+4KB, +544KB): Wfrag 384KB | pebf 32KB | Wofrag 128KB
// ---------------------------------------------------------------------------
extern "C" void kernel_launch(void* const* d_in, const int* in_sizes, int n_in,
                              void* d_out, int out_size, void* d_ws, size_t ws_size,
                              hipStream_t stream)
{
    const float* x  = (const float*)d_in[0];
    const float* Wq = (const float*)d_in[1];
    const float* Wk = (const float*)d_in[2];
    const float* Wv = (const float*)d_in[3];
    const float* Wo = (const float*)d_in[4];
    const float* pe = (const float*)d_in[5];
    float* out = (float*)d_out;

    char* ws = (char*)d_ws;
    unsigned short* QA = (unsigned short*)ws;
    unsigned short* Kd = (unsigned short*)(ws + (8u << 20));
    unsigned short* Vt = (unsigned short*)(ws + (16u << 20));
    char* fr = ws + (24u << 20) + 4096;
    __hip_bfloat16* Wfrag  = (__hip_bfloat16*)fr;
    __hip_bfloat16* pebf   = (__hip_bfloat16*)(fr + (384u << 10));
    __hip_bfloat16* Wofrag = (__hip_bfloat16*)(fr + (416u << 10));

    convert_kernel<<<136, 256, 0, stream>>>(Wq, Wk, Wv, Wo, pe, Wfrag, pebf, Wofrag);
    qkv_mfma<<<dim3(256, 3), 256, 0, stream>>>(x, Wfrag, pe, QA, Kd, Vt);
    attn_oproj<<<1024, 512, 0, stream>>>(QA, Kd, Vt, pebf, Wofrag, out);
}